// Round 8
// baseline (564.441 us; speedup 1.0000x reference)
//
#include <hip/hip_runtime.h>
#include <hip/hip_bf16.h>
#include <stdint.h>

// FeatureVolume: trilinear grid_sample of fm [32,129,129,129] at 1M points.
// R7 baseline: transpose fm -> [DHW,32] bf16 vol in d_ws (L3-resident), gather
// 8 corners/point (8 lanes x uint2). 523us total, sample ~150-165us, miss-path
// bound (random order -> ~3% L2 hit).
// R8: Morton-bucket the points (32^3 buckets of 4^3 cells) so sample walks the
// volume spatially; chunked XCD swizzle keeps each XCD's L2 on a compact slab.
// Chain: transpose(+hist zero) -> hist -> scan -> scatter -> sample_sorted.

#define GRIDW 129
#define S_TOTAL (129 * 129 * 129)  // 2146689
#define NCH 32
#define NB 32768                   // 32^3 Morton buckets
#define NXCD 8

typedef float f32x4 __attribute__((ext_vector_type(4)));

static __device__ __forceinline__ ushort f32_to_bf16_rne(float f) {
    uint32_t u = __float_as_uint(f);
    u += 0x7FFFu + ((u >> 16) & 1u);
    return (ushort)(u >> 16);
}

static __device__ __forceinline__ uint32_t part1by2(uint32_t x) {
    x &= 0x3ffu;
    x = (x | (x << 16)) & 0x30000FFu;
    x = (x | (x << 8))  & 0x300F00Fu;
    x = (x | (x << 4))  & 0x30C30C3u;
    x = (x | (x << 2))  & 0x9249249u;
    return x;
}

// Shared coordinate prep; MUST be identical in hist and sample.
static __device__ __forceinline__ void prep_coords(float cx, float cy, float cz,
                                                   int& ix0, int& iy0, int& iz0,
                                                   float& tx, float& ty, float& tz) {
    const float fx = fminf(fmaxf((cx + 1.0f) * 0.5f * 128.0f, 0.0f), 128.0f);
    const float fy = fminf(fmaxf((cy + 1.0f) * 0.5f * 128.0f, 0.0f), 128.0f);
    const float fz = fminf(fmaxf((cz + 1.0f) * 0.5f * 128.0f, 0.0f), 128.0f);
    const float fx0 = floorf(fx), fy0 = floorf(fy), fz0 = floorf(fz);
    ix0 = (int)fx0; iy0 = (int)fy0; iz0 = (int)fz0;
    tx = fx - fx0; ty = fy - fy0; tz = fz - fz0;
}

static __device__ __forceinline__ uint32_t bucket_of(int ix0, int iy0, int iz0) {
    const uint32_t bx = min((uint32_t)ix0 >> 2, 31u);
    const uint32_t by = min((uint32_t)iy0 >> 2, 31u);
    const uint32_t bz = min((uint32_t)iz0 >> 2, 31u);
    return (part1by2(bz) << 2) | (part1by2(by) << 1) | part1by2(bx);
}

// fm [32][S] f32 -> vol [S][32] bf16. Also zeroes the bucket histogram
// (first 128 blocks) so no separate dispatch is needed.
__global__ __launch_bounds__(256) void fv_transpose(const float* __restrict__ fm,
                                                    ushort* __restrict__ vol,
                                                    uint32_t* __restrict__ hist) {
    const int tid = threadIdx.x;
    if (blockIdx.x < NB / 256) hist[blockIdx.x * 256 + tid] = 0;

    __shared__ float tile[256 * 33];
    const int s0 = blockIdx.x * 256;
    const int s = min(s0 + tid, S_TOTAL - 1);
    const float* p = fm + s;
#pragma unroll
    for (int c = 0; c < NCH; ++c) {
        tile[tid * 33 + c] = __builtin_nontemporal_load(p);  // fm read-once
        p += S_TOTAL;
    }
    __syncthreads();
    const int sl = tid >> 2;
    const int c0 = (tid & 3) * 8;
#pragma unroll
    for (int k = 0; k < 4; ++k) {
        const int srow = k * 64 + sl;
        const int sg = s0 + srow;
        if (sg < S_TOTAL) {
            uint32_t w[4];
#pragma unroll
            for (int j = 0; j < 4; ++j) {
                const ushort lo = f32_to_bf16_rne(tile[srow * 33 + c0 + 2 * j]);
                const ushort hi = f32_to_bf16_rne(tile[srow * 33 + c0 + 2 * j + 1]);
                w[j] = (uint32_t)lo | ((uint32_t)hi << 16);
            }
            *reinterpret_cast<uint4*>(vol + (size_t)sg * NCH + c0) =
                make_uint4(w[0], w[1], w[2], w[3]);
        }
    }
}

// Pass 1: bucket id per point + histogram.
__global__ __launch_bounds__(256) void fv_hist(const float* __restrict__ x,
                                               uint32_t* __restrict__ hist,
                                               ushort* __restrict__ bkt, int npts) {
    const int p = blockIdx.x * 256 + threadIdx.x;
    if (p >= npts) return;
    int ix0, iy0, iz0; float tx, ty, tz;
    prep_coords(x[3 * p], x[3 * p + 1], x[3 * p + 2], ix0, iy0, iz0, tx, ty, tz);
    const uint32_t b = bucket_of(ix0, iy0, iz0);
    bkt[p] = (ushort)b;
    atomicAdd(&hist[b], 1u);
}

// Pass 2: exclusive prefix over NB buckets -> cursor (single 1024-thread block).
__global__ __launch_bounds__(1024) void fv_scan(const uint32_t* __restrict__ hist,
                                                uint32_t* __restrict__ cursor) {
    __shared__ uint32_t part[1024];
    const int t = threadIdx.x;
    const int base = t * (NB / 1024);
    uint32_t l[NB / 1024];
    uint32_t s = 0;
#pragma unroll
    for (int k = 0; k < NB / 1024; ++k) { l[k] = hist[base + k]; s += l[k]; }
    part[t] = s;
    __syncthreads();
    for (int off = 1; off < 1024; off <<= 1) {
        const uint32_t v = (t >= off) ? part[t - off] : 0u;
        __syncthreads();
        part[t] += v;
        __syncthreads();
    }
    uint32_t run = part[t] - s;  // exclusive prefix of this thread's chunk
#pragma unroll
    for (int k = 0; k < NB / 1024; ++k) { cursor[base + k] = run; run += l[k]; }
}

// Pass 3: scatter points into bucket order as (x,y,z, orig-idx) records.
__global__ __launch_bounds__(256) void fv_scatter(const float* __restrict__ x,
                                                  const ushort* __restrict__ bkt,
                                                  uint32_t* __restrict__ cursor,
                                                  f32x4* __restrict__ srt, int npts) {
    const int p = blockIdx.x * 256 + threadIdx.x;
    if (p >= npts) return;
    const uint32_t b = bkt[p];
    const uint32_t pos = atomicAdd(&cursor[b], 1u);
    f32x4 v = {x[3 * p], x[3 * p + 1], x[3 * p + 2], __uint_as_float((uint32_t)p)};
    srt[pos] = v;
}

static __device__ __forceinline__ void bf16x4_to_f(uint2 q, float f[4]) {
    f[0] = __uint_as_float(q.x << 16);
    f[1] = __uint_as_float(q.x & 0xFFFF0000u);
    f[2] = __uint_as_float(q.y << 16);
    f[3] = __uint_as_float(q.y & 0xFFFF0000u);
}

// Sample in bucket order. 8 lanes/point, 4 ch/lane; chunked XCD swizzle keeps
// each XCD's L2 on a contiguous spatial slab of the sorted order.
__global__ __launch_bounds__(256) void fv_sample_sorted(const f32x4* __restrict__ srt,
                                                        const ushort* __restrict__ vol,
                                                        float* __restrict__ out,
                                                        int npts, int nwg) {
    // bijective XCD swizzle (m204): hw block b -> sorted-chunk block
    const int b = blockIdx.x;
    const int q = nwg / NXCD, r = nwg % NXCD;
    const int xcd = b % NXCD, local = b / NXCD;
    const int swz = (xcd < r) ? (xcd * (q + 1) + local) : (r * (q + 1) + (xcd - r) * q + local);

    const int gid = swz * 256 + threadIdx.x;
    const int i = gid >> 3;  // sorted position
    if (i >= npts) return;
    const int lane8 = gid & 7;

    const f32x4 rec = srt[i];
    const uint32_t p = __float_as_uint(rec.w);

    int ix0, iy0, iz0; float tx, ty, tz;
    prep_coords(rec.x, rec.y, rec.z, ix0, iy0, iz0, tx, ty, tz);

    const uint32_t dX = (ix0 < GRIDW - 1) ? 8u : 0u;            // uint2 units
    const uint32_t dY = (iy0 < GRIDW - 1) ? (GRIDW * 8u) : 0u;
    const uint32_t dZ = (iz0 < GRIDW - 1) ? (GRIDW * GRIDW * 8u) : 0u;

    const uint32_t o000 = (uint32_t)((iz0 * GRIDW + iy0) * GRIDW + ix0) * 8u + (uint32_t)lane8;
    const uint32_t o001 = o000 + dX;
    const uint32_t o010 = o000 + dY;
    const uint32_t o011 = o010 + dX;
    const uint32_t o100 = o000 + dZ;
    const uint32_t o101 = o100 + dX;
    const uint32_t o110 = o100 + dY;
    const uint32_t o111 = o110 + dX;

    const uint2* __restrict__ vp = reinterpret_cast<const uint2*>(vol);
    const uint2 q000 = vp[o000];
    const uint2 q001 = vp[o001];
    const uint2 q010 = vp[o010];
    const uint2 q011 = vp[o011];
    const uint2 q100 = vp[o100];
    const uint2 q101 = vp[o101];
    const uint2 q110 = vp[o110];
    const uint2 q111 = vp[o111];

    const float wx1 = tx, wx0 = 1.0f - tx;
    const float wy1 = ty, wy0 = 1.0f - ty;
    const float wz1 = tz, wz0 = 1.0f - tz;
    const float wzy00 = wz0 * wy0, wzy01 = wz0 * wy1;
    const float wzy10 = wz1 * wy0, wzy11 = wz1 * wy1;
    const float w000 = wzy00 * wx0, w001 = wzy00 * wx1;
    const float w010 = wzy01 * wx0, w011 = wzy01 * wx1;
    const float w100 = wzy10 * wx0, w101 = wzy10 * wx1;
    const float w110 = wzy11 * wx0, w111 = wzy11 * wx1;

    float f[4], acc[4];
    bf16x4_to_f(q000, f);
#pragma unroll
    for (int j = 0; j < 4; ++j) acc[j] = w000 * f[j];
    bf16x4_to_f(q001, f);
#pragma unroll
    for (int j = 0; j < 4; ++j) acc[j] += w001 * f[j];
    bf16x4_to_f(q010, f);
#pragma unroll
    for (int j = 0; j < 4; ++j) acc[j] += w010 * f[j];
    bf16x4_to_f(q011, f);
#pragma unroll
    for (int j = 0; j < 4; ++j) acc[j] += w011 * f[j];
    bf16x4_to_f(q100, f);
#pragma unroll
    for (int j = 0; j < 4; ++j) acc[j] += w100 * f[j];
    bf16x4_to_f(q101, f);
#pragma unroll
    for (int j = 0; j < 4; ++j) acc[j] += w101 * f[j];
    bf16x4_to_f(q110, f);
#pragma unroll
    for (int j = 0; j < 4; ++j) acc[j] += w110 * f[j];
    bf16x4_to_f(q111, f);
#pragma unroll
    for (int j = 0; j < 4; ++j) acc[j] += w111 * f[j];

    f32x4 res = {acc[0], acc[1], acc[2], acc[3]};
    f32x4* dst = reinterpret_cast<f32x4*>(out + (size_t)p * NCH) + lane8;
    __builtin_nontemporal_store(res, dst);  // out never re-read
}

// Fallback: gather directly from fm [C][S] f32 (ws too small).
__global__ __launch_bounds__(256) void fv_sample_direct(const float* __restrict__ x,
                                                        const float* __restrict__ fm,
                                                        float* __restrict__ out,
                                                        int npts) {
    const int gid = blockIdx.x * 256 + threadIdx.x;
    const int p = gid >> 5;
    if (p >= npts) return;
    const int c = gid & 31;
    int ix0, iy0, iz0; float tx, ty, tz;
    prep_coords(x[3 * p], x[3 * p + 1], x[3 * p + 2], ix0, iy0, iz0, tx, ty, tz);
    const int dX = (ix0 < GRIDW - 1) ? 1 : 0;
    const int dY = (iy0 < GRIDW - 1) ? GRIDW : 0;
    const int dZ = (iz0 < GRIDW - 1) ? (GRIDW * GRIDW) : 0;
    const int s000 = (iz0 * GRIDW + iy0) * GRIDW + ix0;
    const float* b = fm + (size_t)c * S_TOTAL;
    const float v000 = b[s000];
    const float v001 = b[s000 + dX];
    const float v010 = b[s000 + dY];
    const float v011 = b[s000 + dY + dX];
    const float v100 = b[s000 + dZ];
    const float v101 = b[s000 + dZ + dX];
    const float v110 = b[s000 + dZ + dY];
    const float v111 = b[s000 + dZ + dY + dX];
    const float wx1 = tx, wx0 = 1.0f - tx;
    const float wy1 = ty, wy0 = 1.0f - ty;
    const float wz1 = tz, wz0 = 1.0f - tz;
    const float r = v000 * (wz0 * wy0 * wx0) + v001 * (wz0 * wy0 * wx1) +
                    v010 * (wz0 * wy1 * wx0) + v011 * (wz0 * wy1 * wx1) +
                    v100 * (wz1 * wy0 * wx0) + v101 * (wz1 * wy0 * wx1) +
                    v110 * (wz1 * wy1 * wx0) + v111 * (wz1 * wy1 * wx1);
    out[(size_t)p * NCH + c] = r;
}

extern "C" void kernel_launch(void* const* d_in, const int* in_sizes, int n_in,
                              void* d_out, int out_size, void* d_ws, size_t ws_size,
                              hipStream_t stream) {
    const float* x = (const float*)d_in[0];
    const float* fm = (const float*)d_in[1];
    float* out = (float*)d_out;
    const int npts = in_sizes[0] / 3;

    // ws layout (bytes):
    //   [0, 137.4MB)   vol bf16 [S][32]
    //   HIST_OFF       hist  (NB u32)
    //   +NB*4          cursor(NB u32)
    //   +2MB           bkt   (npts u16)
    //   +8MB           srt   (npts f32x4)
    const size_t HIST_OFF = 144u * 1024u * 1024u;
    const size_t need = HIST_OFF + 8u * 1024u * 1024u + (size_t)npts * 16u;
    if (ws_size >= need) {
        ushort* vol = (ushort*)d_ws;
        uint32_t* hist = (uint32_t*)((char*)d_ws + HIST_OFF);
        uint32_t* cursor = (uint32_t*)((char*)d_ws + HIST_OFF + (size_t)NB * 4u);
        ushort* bkt = (ushort*)((char*)d_ws + HIST_OFF + 2u * 1024u * 1024u);
        f32x4* srt = (f32x4*)((char*)d_ws + HIST_OFF + 8u * 1024u * 1024u);

        const int tb = (S_TOTAL + 255) / 256;
        fv_transpose<<<tb, 256, 0, stream>>>(fm, vol, hist);
        const int pb = (npts + 255) / 256;
        fv_hist<<<pb, 256, 0, stream>>>(x, hist, bkt, npts);
        fv_scan<<<1, 1024, 0, stream>>>(hist, cursor);
        fv_scatter<<<pb, 256, 0, stream>>>(x, bkt, cursor, srt, npts);
        const int nwg = (npts * 8 + 255) / 256;
        fv_sample_sorted<<<nwg, 256, 0, stream>>>(srt, vol, out, npts, nwg);
    } else {
        const int nthreads = npts * 32;
        fv_sample_direct<<<(nthreads + 255) / 256, 256, 0, stream>>>(x, fm, out, npts);
    }
}